// Round 6
// baseline (183.504 us; speedup 1.0000x reference)
//
#include <hip/hip_runtime.h>
#include <hip/hip_cooperative_groups.h>

namespace cg = cooperative_groups;

#define M_PAD 512

// Single cooperative kernel:
//   Phase 1 (grid-stride over T): run-boundary detection on sorted ri.
//     start[r] = first i with ri[i]==r ; endx[r] = last+1.
//     Boundary threads also zero start/endx for gap rays (absent from ri),
//     so no memset of d_ws is needed (expected gap per boundary ~0-1 rays).
//   grid.sync()
//   Phase 2 (grid-stride over N*512): dense output sweep, one slot/thread.
//     Valid slots gather i = start[r]+j (lane-consecutive -> dense loads),
//     compute z/dist/xyz, write xyz_out[i] (bijection onto [0,T)).
//     All stores lane-consecutive: no partial-line RMW, no second pass.
__global__ __launch_bounds__(256, 4)
void mono_kernel(const float* __restrict__ rays,
                 const int* __restrict__ ri,
                 const float* __restrict__ ts,
                 const float* __restrict__ te,
                 int* __restrict__ start,
                 int* __restrict__ endx,
                 float* __restrict__ xyz_out,     // (T,4)
                 float* __restrict__ ray_valid,   // (N,512)
                 float* __restrict__ z_vals,      // (N,512)
                 float* __restrict__ dists,       // (N,512)
                 float* __restrict__ xyz_w,       // (N,512,4)
                 float* __restrict__ whole_valid, // (N,)
                 int N, int T) {
    cg::grid_group grid = cg::this_grid();
    const int gsize = gridDim.x * blockDim.x;
    const int tid = blockIdx.x * blockDim.x + threadIdx.x;

    // ---- Phase 1: boundaries + gap zeroing ----
    for (int i = tid; i < T; i += gsize) {
        int r = ri[i];
        if (i == 0) {
            start[r] = 0;
            for (int g = 0; g < r; ++g) { start[g] = 0; endx[g] = 0; }
        } else {
            int rp = ri[i - 1];
            if (rp != r) {
                start[r] = i;
                endx[rp] = i;
                for (int g = rp + 1; g < r; ++g) { start[g] = 0; endx[g] = 0; }
            }
        }
        if (i == T - 1) {
            endx[r] = T;
            for (int g = r + 1; g < N; ++g) { start[g] = 0; endx[g] = 0; }
        }
    }

    grid.sync();

    // ---- Phase 2: dense fused output sweep ----
    const int total = N * M_PAD;
    for (int idx = tid; idx < total; idx += gsize) {
        int r = idx >> 9;                 // 512 slots per ray
        int j = idx & (M_PAD - 1);
        int s = start[r];
        int cnt = endx[r] - s;

        float z = 0.0f, dd = 0.0f, v = 0.0f;
        float4 pt = make_float4(0.f, 0.f, 0.f, 0.f);

        if (j < cnt) {
            int i = s + j;
            float a = ts[i], b = te[i];
            z  = (a + b) * 0.5f;
            dd = b - a;
            v  = 1.0f;
            const float* rc = rays + (size_t)r * 6;   // wave-uniform -> L1 broadcast
            pt = make_float4(fmaf(z, rc[3], rc[0]),
                             fmaf(z, rc[4], rc[1]),
                             fmaf(z, rc[5], rc[2]), 0.0f);
            reinterpret_cast<float4*>(xyz_out)[i] = pt;   // dense across lanes
        }

        z_vals[idx]    = z;
        dists[idx]     = dd;
        ray_valid[idx] = v;
        reinterpret_cast<float4*>(xyz_w)[idx] = pt;       // dense 16B/lane

        if (j == 0) whole_valid[r] = 1.0f;
    }
}

extern "C" void kernel_launch(void* const* d_in, const int* in_sizes, int n_in,
                              void* d_out, int out_size, void* d_ws, size_t ws_size,
                              hipStream_t stream) {
    const float* rays = (const float*)d_in[0];  // (N,6)
    const int*   ri   = (const int*)d_in[1];    // (T,) sorted
    const float* ts   = (const float*)d_in[2];  // (T,)
    const float* te   = (const float*)d_in[3];  // (T,)
    int N = in_sizes[0] / 6;
    int T = in_sizes[1];

    float* out         = (float*)d_out;
    float* xyz_out     = out;                                    // T*4
    float* ray_valid   = xyz_out + (size_t)T * 4;                // N*512
    float* z_vals      = ray_valid + (size_t)N * M_PAD;          // N*512
    float* dists       = z_vals + (size_t)N * M_PAD;             // N*512
    float* whole_valid = dists + (size_t)N * M_PAD;              // N
    float* xyz_w       = whole_valid + N;                        // N*512*4

    int* start = (int*)d_ws;
    int* endx  = start + N;

    void* args[] = {
        (void*)&rays, (void*)&ri, (void*)&ts, (void*)&te,
        (void*)&start, (void*)&endx,
        (void*)&xyz_out, (void*)&ray_valid, (void*)&z_vals,
        (void*)&dists, (void*)&xyz_w, (void*)&whole_valid,
        (void*)&N, (void*)&T
    };
    hipLaunchCooperativeKernel((const void*)mono_kernel,
                               dim3(1024), dim3(256), args, 0, stream);
}

// Round 10
// 71.983 us; speedup vs baseline: 2.5493x; 2.5493x over previous
//
#include <hip/hip_runtime.h>

#define M_PAD 512

typedef float f32x4 __attribute__((ext_vector_type(4)));

// Pass 1: run-boundary detection over sorted ri, WITH gap-ray zeroing
// (rays absent from ri get start=endx=0), so no d_ws memset dispatch.
// Expected gap per boundary ~0-1 rays (T/N = 256).
__global__ void boundary_kernel(const int* __restrict__ ri,
                                int* __restrict__ start, int* __restrict__ endx,
                                int N, int T) {
    int i = blockIdx.x * blockDim.x + threadIdx.x;
    if (i >= T) return;
    int r = ri[i];
    if (i == 0) {
        start[r] = 0;
        for (int g = 0; g < r; ++g) { start[g] = 0; endx[g] = 0; }
    } else {
        int rp = ri[i - 1];
        if (rp != r) {
            start[r] = i;
            endx[rp] = i;
            for (int g = rp + 1; g < r; ++g) { start[g] = 0; endx[g] = 0; }
        }
    }
    if (i == T - 1) {
        endx[r] = T;
        for (int g = r + 1; g < N; ++g) { start[g] = 0; endx[g] = 0; }
    }
}

// Pass 2 (fused, one slot per thread, dense lane-consecutive stores),
// all output stores nontemporal: outputs are write-once, never re-read ->
// bypass L2 allocation pressure from ~300 MB of streaming stores.
__global__ void fused_kernel(const float* __restrict__ rays,
                             const float* __restrict__ ts,
                             const float* __restrict__ te,
                             const int* __restrict__ start,
                             const int* __restrict__ endx,
                             float* __restrict__ xyz_out,     // (T,4)
                             float* __restrict__ ray_valid,   // (N,512)
                             float* __restrict__ z_vals,      // (N,512)
                             float* __restrict__ dists,       // (N,512)
                             float* __restrict__ xyz_w,       // (N,512,4)
                             float* __restrict__ whole_valid, // (N,)
                             int total) {
    int idx = blockIdx.x * blockDim.x + threadIdx.x;
    if (idx >= total) return;
    int r = idx >> 9;            // 512 slots per ray; wave64 = 1/8 ray (uniform r)
    int j = idx & (M_PAD - 1);
    int s = start[r];
    int cnt = endx[r] - s;

    float z = 0.0f, dd = 0.0f, v = 0.0f;
    f32x4 pt = {0.f, 0.f, 0.f, 0.f};

    if (j < cnt) {
        int i = s + j;
        float a = ts[i], b = te[i];
        z  = (a + b) * 0.5f;
        dd = b - a;
        v  = 1.0f;
        const float* rc = rays + (size_t)r * 6;   // wave-uniform -> L1 broadcast
        pt.x = fmaf(z, rc[3], rc[0]);
        pt.y = fmaf(z, rc[4], rc[1]);
        pt.z = fmaf(z, rc[5], rc[2]);
        __builtin_nontemporal_store(pt, reinterpret_cast<f32x4*>(xyz_out) + i);
    }

    __builtin_nontemporal_store(z,  &z_vals[idx]);
    __builtin_nontemporal_store(dd, &dists[idx]);
    __builtin_nontemporal_store(v,  &ray_valid[idx]);
    __builtin_nontemporal_store(pt, reinterpret_cast<f32x4*>(xyz_w) + idx);

    if (j == 0) whole_valid[r] = 1.0f;
}

extern "C" void kernel_launch(void* const* d_in, const int* in_sizes, int n_in,
                              void* d_out, int out_size, void* d_ws, size_t ws_size,
                              hipStream_t stream) {
    const float* rays = (const float*)d_in[0];  // (N,6)
    const int*   ri   = (const int*)d_in[1];    // (T,) sorted
    const float* ts   = (const float*)d_in[2];  // (T,)
    const float* te   = (const float*)d_in[3];  // (T,)
    const int N = in_sizes[0] / 6;
    const int T = in_sizes[1];

    float* out         = (float*)d_out;
    float* xyz_out     = out;                                    // T*4
    float* ray_valid   = xyz_out + (size_t)T * 4;                // N*512
    float* z_vals      = ray_valid + (size_t)N * M_PAD;          // N*512
    float* dists       = z_vals + (size_t)N * M_PAD;             // N*512
    float* whole_valid = dists + (size_t)N * M_PAD;              // N
    float* xyz_w       = whole_valid + N;                        // N*512*4

    int* start = (int*)d_ws;
    int* endx  = start + N;

    const int B = 256;
    boundary_kernel<<<(T + B - 1) / B, B, 0, stream>>>(ri, start, endx, N, T);
    const int total = N * M_PAD;
    fused_kernel<<<(total + B - 1) / B, B, 0, stream>>>(rays, ts, te, start, endx,
                                                        xyz_out, ray_valid, z_vals,
                                                        dists, xyz_w, whole_valid,
                                                        total);
}